// Round 4
// baseline (176.761 us; speedup 1.0000x reference)
//
#include <hip/hip_runtime.h>
#include <hip/hip_bf16.h>

using bf16x8 = __attribute__((ext_vector_type(8))) short;
using f32x4  = __attribute__((ext_vector_type(4))) float;

constexpr int CH  = 64;
constexpr int HW  = 11;
constexpr int NP  = 121;
constexpr int PPW = 14;    // padded pos row width
constexpr int NPP = 182;   // padded positions (13x14)
constexpr int ICP = 72;    // padded ic stride (bf16) in LDS
constexpr int NO  = 7168;  // padded o rows (112 oc * 64 ic)
constexpr int NT  = NO / 16;   // 448 gen tiles
constexpr int MT  = 7;     // main M-tiles (112 oc rows)
constexpr int KS  = 18;    // main k-steps (9 taps x 2 halves of 32)
constexpr float EPS = 1e-5f;
// Wfrag: per sample MT*KS*64 fragments of 16B = 129024 B
constexpr int FRAGS_PS = MT * KS * 64;
// ws requirement: 458752 (Aprep) + 28672 (Beta) + 1024*129024 (Wfrag) ~= 126.5 MiB

// ---- prep: bake BN-scaled gw into gen-MFMA A-fragment order + beta ----
__global__ __launch_bounds__(256) void prep_kernel(
    const float* __restrict__ gw, const float* __restrict__ gb,
    const float* __restrict__ bng, const float* __restrict__ bnb,
    const float* __restrict__ bnm, const float* __restrict__ bnv,
    unsigned short* __restrict__ Aprep, float* __restrict__ Beta)
{
    int o = blockIdx.x * 256 + threadIdx.x;   // padded o = oc*64+ic, oc<112
    if (o >= NO) return;
    float inv = 0.f, beta = 0.f;
    if (o < 6400) {
        inv  = bng[o] * rsqrtf(bnv[o] + EPS);
        beta = (gb[o] - bnm[o]) * inv + bnb[o];
    }
    Beta[o] = beta;
    int tile = o >> 4, lrow = o & 15;
    #pragma unroll
    for (int jg = 0; jg < 4; ++jg) {
        bf16x8 f;
        #pragma unroll
        for (int r = 0; r < 8; ++r) {
            int k = jg * 8 + r;
            float v = (o < 6400 && k < 18) ? gw[(size_t)o * 18 + k] * inv : 0.f;
            __hip_bfloat16 h = __float2bfloat16(v);
            f[r] = *(short*)&h;
        }
        ((bf16x8*)Aprep)[tile * 64 + jg * 16 + lrow] = f;
    }
}

// ---- GEN: pool + filter-gen, emit W as main-A-fragments to ws ----
__global__ __launch_bounds__(256, 2) void hsi_gen(
    const float* __restrict__ x_in,
    const unsigned short* __restrict__ Aprep,
    const float* __restrict__ Beta,
    unsigned short* __restrict__ Wfrag)
{
    __shared__ alignas(16) unsigned short Wlds[9][32][ICP]; // 41472 B (one oc-chunk)
    __shared__ alignas(16) unsigned short BgenT[16][40];
    __shared__ float xh[2][128];
    __shared__ float xhp[2][2][128];

    const int b = blockIdx.x, t = threadIdx.x;
    const int lane = t & 63, wave = t >> 6;
    const int lrow = lane & 15, jg = lane >> 4;
    const float* xb = x_in + (size_t)b * (CH * NP);

    if (t < 320) ((unsigned int*)BgenT)[t] = 0u;
    // exact fp32 pooling, coalesced (lane -> position)
    {
        int p = (wave & 1) * 64 + lane;
        int ich = wave >> 1;
        if (p < NP) {
            float s = 0.f, m = -INFINITY;
            const float* xc = xb + (ich * 32) * NP + p;
            #pragma unroll 8
            for (int q = 0; q < 32; ++q) {
                float v = xc[q * NP];
                s += v; m = fmaxf(m, v);
            }
            xhp[ich][0][p] = s;
            xhp[ich][1][p] = m;
        }
    }
    __syncthreads();
    if (t < NP) {
        xh[0][t] = (xhp[0][0][t] + xhp[1][0][t]) * (1.f / 64.f);
        xh[1][t] = fmaxf(xhp[0][1][t], xhp[1][1][t]);
    }
    __syncthreads();
    if (t < 162) {   // gen-GEMM B: BgenT[tap][k], k = ci*9+u*3+v (gw flat order)
        int tap = t / 18, k = t - tap * 18;
        int ci = k / 9, o9 = k - ci * 9, u = o9 / 3, v = o9 - u * 3;
        int kh = tap / 3, kw = tap - kh * 3;
        float val = xh[ci][(4 * kh + u) * HW + (4 * kw + v)];
        __hip_bfloat16 h = __float2bfloat16(val);
        BgenT[tap][k] = *(unsigned short*)&h;
    }
    __syncthreads();
    bf16x8 Bgen = *(const bf16x8*)&BgenT[lrow][jg * 8];

    unsigned short* wfb = Wfrag + (size_t)b * FRAGS_PS * 8;

    for (int c = 0; c < 4; ++c) {
        // gen-MFMA: chunk c covers ocs 32c..; c==3 only needs ocs 96..111 (16 ocs)
        const int nIt = (c < 3) ? 32 : 16;
        #pragma unroll 4
        for (int it = 0; it < nIt; ++it) {
            int tl = wave * nIt + it;            // chunk-local tile
            int tG = c * 128 + tl;               // global tile, < 448 (in bounds)
            bf16x8 A = *(const bf16x8*)(Aprep + ((size_t)tG * 64 + lane) * 8);
            f32x4 acc{};
            acc = __builtin_amdgcn_mfma_f32_16x16x32_bf16(A, Bgen, acc, 0, 0, 0);
            if (lrow < 9) {   // C col = tap
                int ol = tl * 16 + jg * 4;       // chunk-local o
                float4 bet = *(const float4*)(Beta + c * 2048 + ol);
                float v0 = fmaxf(acc[0] + bet.x, 0.f);
                float v1 = fmaxf(acc[1] + bet.y, 0.f);
                float v2 = fmaxf(acc[2] + bet.z, 0.f);
                float v3 = fmaxf(acc[3] + bet.w, 0.f);
                __hip_bfloat16 h0 = __float2bfloat16(v0), h1 = __float2bfloat16(v1);
                __hip_bfloat16 h2 = __float2bfloat16(v2), h3 = __float2bfloat16(v3);
                unsigned int lo = (unsigned int)*(unsigned short*)&h0 |
                                  ((unsigned int)*(unsigned short*)&h1 << 16);
                unsigned int hi = (unsigned int)*(unsigned short*)&h2 |
                                  ((unsigned int)*(unsigned short*)&h3 << 16);
                int icb = (ol & 63) ^ ((lrow & 7) << 3);   // tap-XOR, 8-elem granule
                uint2 pk; pk.x = lo; pk.y = hi;
                *(uint2*)&Wlds[lrow][ol >> 6][icb] = pk;
            }
        }
        __syncthreads();
        // readback Wlds -> Wfrag (main-A-frag layout), coalesced dwordx4 stores
        const int nTask = (c < 3) ? 36 : 18;     // (mi, ks) pairs; c==3: mi=0 only
        for (int j = wave; j < nTask; j += 4) {
            int mi = j / KS, ks = j - mi * KS;
            int m = c * 2 + mi;                  // < 7
            int tap = ks >> 1, h = ks & 1;
            int kk = (h * 32 + jg * 8) ^ ((tap & 7) << 3);
            bf16x8 f = *(const bf16x8*)&Wlds[tap][mi * 16 + lrow][kk];
            *(bf16x8*)(wfb + ((size_t)(m * KS + ks) * 64 + lane) * 8) = f;
        }
        __syncthreads();
    }
}

// ---- MAIN: per-sample GEMM, A in registers, B from LDS, 2 barriers total ----
__global__ __launch_bounds__(256, 1) void hsi_main(
    const float* __restrict__ x_in,
    const unsigned short* __restrict__ Wfrag,
    float* __restrict__ out)
{
    __shared__ alignas(16) unsigned short xsT[NPP][ICP];   // 26208 B

    const int b = blockIdx.x, t = threadIdx.x;
    const int lane = t & 63, wave = t >> 6;
    const int lrow = lane & 15, jg = lane >> 4;
    const float* xb = x_in + (size_t)b * (CH * NP);

    // issue A-fragment loads first (L3-hot Wfrag), hide under staging
    const unsigned short* wfb = Wfrag + (size_t)b * FRAGS_PS * 8;
    const int m0 = wave;
    const int m1 = wave + 4;
    const bool has2 = (wave < 3);
    bf16x8 A0[KS], A1[KS];
    #pragma unroll
    for (int ks = 0; ks < KS; ++ks)
        A0[ks] = *(const bf16x8*)(wfb + ((size_t)(m0 * KS + ks) * 64 + lane) * 8);
    if (has2) {
        #pragma unroll
        for (int ks = 0; ks < KS; ++ks)
            A1[ks] = *(const bf16x8*)(wfb + ((size_t)(m1 * KS + ks) * 64 + lane) * 8);
    }

    // stage x: zero-fill padded tile, then bf16 transpose-scatter
    for (int i = t; i < NPP * ICP / 2; i += 256) ((unsigned int*)xsT)[i] = 0u;
    __syncthreads();
    {
        int p = (wave & 1) * 64 + lane;
        int ich = wave >> 1;
        if (p < NP) {
            int pp = (p / HW + 1) * PPW + (p % HW + 1);
            const float* xc = xb + (ich * 32) * NP + p;
            #pragma unroll 8
            for (int q = 0; q < 32; ++q) {
                float v = xc[q * NP];
                __hip_bfloat16 h = __float2bfloat16(v);
                xsT[pp][ich * 32 + q] = *(unsigned short*)&h;
            }
        }
    }
    __syncthreads();

    // GEMM: wave covers M-tiles {m0, m1} x all 8 N-tiles, K=576
    float* ob = out + (size_t)b * 100 * NP;
    #pragma unroll
    for (int nt = 0; nt < 8; ++nt) {
        int p  = nt * 16 + lrow;
        int pc = p > 120 ? 120 : p;
        int base = (pc / HW) * PPW + (pc % HW);
        f32x4 aA{}, aB{};
        #pragma unroll
        for (int tap = 0; tap < 9; ++tap) {
            int roff = base + (tap / 3) * PPW + (tap % 3);
            #pragma unroll
            for (int h = 0; h < 2; ++h) {
                bf16x8 Bf = *(const bf16x8*)&xsT[roff][h * 32 + jg * 8];
                aA = __builtin_amdgcn_mfma_f32_16x16x32_bf16(A0[tap * 2 + h], Bf, aA, 0, 0, 0);
                if (has2)
                    aB = __builtin_amdgcn_mfma_f32_16x16x32_bf16(A1[tap * 2 + h], Bf, aB, 0, 0, 0);
            }
        }
        if (p < NP) {
            #pragma unroll
            for (int ri = 0; ri < 4; ++ri) {      // oc0 = wave*16+jg*4+ri <= 63
                ob[(m0 * 16 + jg * 4 + ri) * NP + p] = aA[ri];
            }
            if (has2) {
                #pragma unroll
                for (int ri = 0; ri < 4; ++ri) {
                    int oc = m1 * 16 + jg * 4 + ri;
                    if (oc < 100) ob[oc * NP + p] = aB[ri];
                }
            }
        }
    }
}

extern "C" void kernel_launch(void* const* d_in, const int* in_sizes, int n_in,
                              void* d_out, int out_size, void* d_ws, size_t ws_size,
                              hipStream_t stream) {
    const float* x  = (const float*)d_in[0];
    const float* gw = (const float*)d_in[1];
    const float* gb = (const float*)d_in[2];
    const float* bg = (const float*)d_in[3];
    const float* bb = (const float*)d_in[4];
    const float* bm = (const float*)d_in[5];
    const float* bv = (const float*)d_in[6];
    float* out = (float*)d_out;

    // ws: Aprep 458752 B | Beta 28672 B | Wfrag 1024*129024 B  (~126.5 MiB)
    unsigned short* Aprep = (unsigned short*)d_ws;
    float* Beta = (float*)((char*)d_ws + 458752);
    unsigned short* Wfrag = (unsigned short*)((char*)d_ws + 458752 + 28672);

    const int nb = in_sizes[0] / (CH * NP);  // 1024

    prep_kernel<<<NO / 256, 256, 0, stream>>>(gw, gb, bg, bb, bm, bv, Aprep, Beta);
    hsi_gen<<<nb, 256, 0, stream>>>(x, Aprep, Beta, Wfrag);
    hsi_main<<<nb, 256, 0, stream>>>(x, Wfrag, out);
}

// Round 5
// 129.337 us; speedup vs baseline: 1.3667x; 1.3667x over previous
//
#include <hip/hip_runtime.h>
#include <hip/hip_bf16.h>

using bf16x8 = __attribute__((ext_vector_type(8))) short;
using f32x4  = __attribute__((ext_vector_type(4))) float;

constexpr int CH  = 64;
constexpr int HW  = 11;
constexpr int NP  = 121;
constexpr int PPW = 14;    // padded pos row width
constexpr int NPP = 182;   // padded positions (13x14)
constexpr int ICP = 72;    // padded ic stride (bf16) for xsT
constexpr int NO  = 7168;  // padded o rows (112 oc * 64 ic)
constexpr int NCH = 7;     // 7 chunks x 16 ocs
constexpr float EPS = 1e-5f;

// ---- prep: bake BN-scaled gw into gen-MFMA A-fragment order + beta ----
__global__ __launch_bounds__(256) void prep_kernel(
    const float* __restrict__ gw, const float* __restrict__ gb,
    const float* __restrict__ bng, const float* __restrict__ bnb,
    const float* __restrict__ bnm, const float* __restrict__ bnv,
    unsigned short* __restrict__ Aprep, float* __restrict__ Beta)
{
    int o = blockIdx.x * 256 + threadIdx.x;   // padded o = oc*64+ic, oc<112
    if (o >= NO) return;
    float inv = 0.f, beta = 0.f;
    if (o < 6400) {
        inv  = bng[o] * rsqrtf(bnv[o] + EPS);
        beta = (gb[o] - bnm[o]) * inv + bnb[o];
    }
    Beta[o] = beta;
    int tile = o >> 4, lrow = o & 15;
    #pragma unroll
    for (int jg = 0; jg < 4; ++jg) {
        bf16x8 f;
        #pragma unroll
        for (int r = 0; r < 8; ++r) {
            int k = jg * 8 + r;
            float v = (o < 6400 && k < 18) ? gw[(size_t)o * 18 + k] * inv : 0.f;
            __hip_bfloat16 h = __float2bfloat16(v);
            f[r] = *(short*)&h;
        }
        ((bf16x8*)Aprep)[tile * 64 + jg * 16 + lrow] = f;
    }
}

// ---- fused: pool + gen(MFMA) + main GEMM, software-pipelined chunks ----
__global__ __launch_bounds__(256, 2) void hsi_fused(
    const float* __restrict__ x_in,
    const unsigned short* __restrict__ Aprep,
    const float* __restrict__ Beta,
    float* __restrict__ out)
{
    __shared__ alignas(16) unsigned short xsT[NPP][ICP];      // 26208 B
    __shared__ alignas(16) unsigned short Wc[2][9][16][64];   // 36864 B dbuf
    __shared__ alignas(16) unsigned short BgenT[16][40];      // 1280 B
    __shared__ float xh[2][128];
    __shared__ float xhp[2][2][128];

    const int b = blockIdx.x, t = threadIdx.x;
    const int lane = t & 63, wave = t >> 6;
    const int lrow = lane & 15, jg = lane >> 4;
    const float* xb = x_in + (size_t)b * (CH * NP);

    for (int i = t; i < NPP * ICP / 2; i += 256) ((unsigned int*)xsT)[i] = 0u;
    if (t < 320) ((unsigned int*)BgenT)[t] = 0u;
    __syncthreads();

    // stage x (bf16 transpose) + exact fp32 pool partials, coalesced
    {
        int p = (wave & 1) * 64 + lane, ich = wave >> 1;
        if (p < NP) {
            int pp = (p / HW + 1) * PPW + (p % HW + 1);
            float s = 0.f, m = -INFINITY;
            const float* xc = xb + (ich * 32) * NP + p;
            #pragma unroll 8
            for (int q = 0; q < 32; ++q) {
                float v = xc[q * NP];
                s += v; m = fmaxf(m, v);
                __hip_bfloat16 h = __float2bfloat16(v);
                xsT[pp][ich * 32 + q] = *(unsigned short*)&h;
            }
            xhp[ich][0][p] = s;
            xhp[ich][1][p] = m;
        }
    }
    __syncthreads();
    if (t < NP) {
        xh[0][t] = (xhp[0][0][t] + xhp[1][0][t]) * (1.f / 64.f);
        xh[1][t] = fmaxf(xhp[0][1][t], xhp[1][1][t]);
    }
    __syncthreads();
    if (t < 162) {   // gen-GEMM B: BgenT[tap][k], k = ci*9+u*3+v (gw flat order)
        int tap = t / 18, k = t - tap * 18;
        int ci = k / 9, o9 = k - ci * 9, u = o9 / 3, v = o9 - u * 3;
        int kh = tap / 3, kw = tap - kh * 3;
        float val = xh[ci][(4 * kh + u) * HW + (4 * kw + v)];
        __hip_bfloat16 h = __float2bfloat16(val);
        BgenT[tap][k] = *(unsigned short*)&h;
    }
    __syncthreads();

    const bf16x8 Bgen = *(const bf16x8*)&BgenT[lrow][jg * 8];

    // gen one 16-oc chunk (64 gen-tiles, 16 per wave) into Wc[c1&1]
    auto genchunk = [&](int c1) {
        const int wbuf = c1 & 1;
        #pragma unroll 4
        for (int it = 0; it < 16; ++it) {
            int tl = wave * 16 + it;            // chunk-local gen tile 0..63
            int tG = c1 * 64 + tl;              // global tile < 448
            bf16x8 A = *(const bf16x8*)(Aprep + ((size_t)tG * 64 + lane) * 8);
            f32x4 acc{};
            acc = __builtin_amdgcn_mfma_f32_16x16x32_bf16(A, Bgen, acc, 0, 0, 0);
            float4 bet = *(const float4*)(Beta + tG * 16 + jg * 4);
            if (lrow < 9) {                     // C col = tap
                float v0 = fmaxf(acc[0] + bet.x, 0.f);
                float v1 = fmaxf(acc[1] + bet.y, 0.f);
                float v2 = fmaxf(acc[2] + bet.z, 0.f);
                float v3 = fmaxf(acc[3] + bet.w, 0.f);
                __hip_bfloat16 h0 = __float2bfloat16(v0), h1 = __float2bfloat16(v1);
                __hip_bfloat16 h2 = __float2bfloat16(v2), h3 = __float2bfloat16(v3);
                unsigned int lo = (unsigned int)*(unsigned short*)&h0 |
                                  ((unsigned int)*(unsigned short*)&h1 << 16);
                unsigned int hi = (unsigned int)*(unsigned short*)&h2 |
                                  ((unsigned int)*(unsigned short*)&h3 << 16);
                int oc_l = tl >> 2;             // 0..15
                int g = (2 * (tl & 3) + (jg >> 1)) ^ (lrow & 7) ^ (oc_l & 7);
                uint2 pk; pk.x = lo; pk.y = hi;
                *(uint2*)((char*)&Wc[wbuf][lrow][oc_l][0] + g * 16 + (jg & 1) * 8) = pk;
            }
        }
    };

    // ---- B-frag hoist: 36 bf16x8 in registers, chunk-invariant ----
    bf16x8 Bh[2][18];
    int pst[2];
    #pragma unroll
    for (int nt = 0; nt < 2; ++nt) {
        int p = (wave * 2 + nt) * 16 + lrow;
        pst[nt] = p;
        int pc = p > 120 ? 120 : p;
        int base = (pc / HW) * PPW + (pc % HW);
        #pragma unroll
        for (int tap = 0; tap < 9; ++tap) {
            int roff = base + (tap / 3) * PPW + (tap % 3);
            #pragma unroll
            for (int h = 0; h < 2; ++h)
                Bh[nt][tap * 2 + h] = *(const bf16x8*)&xsT[roff][h * 32 + jg * 8];
        }
    }

    genchunk(0);
    __syncthreads();

    float* ob = out + (size_t)b * 100 * NP;
    for (int c = 0; c < NCH; ++c) {
        // ---- main(c): read A-frags from Wc[c&1], dual-XOR unswizzle ----
        const int rbuf = c & 1;
        f32x4 a0{}, a1{};
        #pragma unroll
        for (int tap = 0; tap < 9; ++tap) {
            #pragma unroll
            for (int h = 0; h < 2; ++h) {
                int g = (h * 4 + jg) ^ (tap & 7) ^ (lrow & 7);
                bf16x8 Af = *(const bf16x8*)((const char*)&Wc[rbuf][tap][lrow][0] + g * 16);
                a0 = __builtin_amdgcn_mfma_f32_16x16x32_bf16(Af, Bh[0][tap*2+h], a0, 0, 0, 0);
                a1 = __builtin_amdgcn_mfma_f32_16x16x32_bf16(Af, Bh[1][tap*2+h], a1, 0, 0, 0);
            }
        }

        // ---- gen(c+1) overlapped (separate buffer, separate pipes) ----
        if (c < NCH - 1) genchunk(c + 1);

        // ---- store main(c): C layout col=lane&15 -> pos, row=jg*4+ri -> oc ----
        #pragma unroll
        for (int nt = 0; nt < 2; ++nt) {
            f32x4 vv = nt == 0 ? a0 : a1;
            int p = pst[nt];
            if (p < NP) {
                #pragma unroll
                for (int ri = 0; ri < 4; ++ri) {
                    int oc = c * 16 + jg * 4 + ri;
                    if (oc < 100) ob[oc * NP + p] = vv[ri];
                }
            }
        }
        if (c < NCH - 1) __syncthreads();
    }
}

extern "C" void kernel_launch(void* const* d_in, const int* in_sizes, int n_in,
                              void* d_out, int out_size, void* d_ws, size_t ws_size,
                              hipStream_t stream) {
    const float* x  = (const float*)d_in[0];
    const float* gw = (const float*)d_in[1];
    const float* gb = (const float*)d_in[2];
    const float* bg = (const float*)d_in[3];
    const float* bb = (const float*)d_in[4];
    const float* bm = (const float*)d_in[5];
    const float* bv = (const float*)d_in[6];
    float* out = (float*)d_out;

    // ws: Aprep 458752 B | Beta 28672 B   (~476 KiB total)
    unsigned short* Aprep = (unsigned short*)d_ws;
    float* Beta = (float*)((char*)d_ws + 458752);

    const int nb = in_sizes[0] / (CH * NP);  // 1024

    prep_kernel<<<NO / 256, 256, 0, stream>>>(gw, gb, bg, bb, bm, bv, Aprep, Beta);
    hsi_fused<<<nb, 256, 0, stream>>>(x, Aprep, Beta, out);
}

// Round 6
// 125.646 us; speedup vs baseline: 1.4068x; 1.0294x over previous
//
#include <hip/hip_runtime.h>
#include <hip/hip_bf16.h>

using bf16x8 = __attribute__((ext_vector_type(8))) short;
using f32x4  = __attribute__((ext_vector_type(4))) float;

constexpr int CH  = 64;
constexpr int HW  = 11;
constexpr int NP  = 121;
constexpr int PPW = 14;    // padded pos row width
constexpr int NPP = 182;   // padded positions (13x14)
constexpr int ICP = 72;    // padded ic stride (bf16) for xsT
constexpr int NO  = 7168;  // padded o rows (112 oc * 64 ic)
constexpr float EPS = 1e-5f;

// ---- prep: bake BN-scaled gw into gen-MFMA A-fragment order + beta ----
__global__ __launch_bounds__(256) void prep_kernel(
    const float* __restrict__ gw, const float* __restrict__ gb,
    const float* __restrict__ bng, const float* __restrict__ bnb,
    const float* __restrict__ bnm, const float* __restrict__ bnv,
    unsigned short* __restrict__ Aprep, float* __restrict__ Beta)
{
    int o = blockIdx.x * 256 + threadIdx.x;   // padded o = oc*64+ic, oc<112
    if (o >= NO) return;
    float inv = 0.f, beta = 0.f;
    if (o < 6400) {
        inv  = bng[o] * rsqrtf(bnv[o] + EPS);
        beta = (gb[o] - bnm[o]) * inv + bnb[o];
    }
    Beta[o] = beta;
    int tile = o >> 4, lrow = o & 15;
    #pragma unroll
    for (int jg = 0; jg < 4; ++jg) {
        bf16x8 f;
        #pragma unroll
        for (int r = 0; r < 8; ++r) {
            int k = jg * 8 + r;
            float v = (o < 6400 && k < 18) ? gw[(size_t)o * 18 + k] * inv : 0.f;
            __hip_bfloat16 h = __float2bfloat16(v);
            f[r] = *(short*)&h;
        }
        ((bf16x8*)Aprep)[tile * 64 + jg * 16 + lrow] = f;
    }
}

// ---- fused: pool + per-wave private gen->GEMM, zero barriers after pooling ----
__global__ __launch_bounds__(512, 1) void hsi_fused(
    const float* __restrict__ x_in,
    const unsigned short* __restrict__ Aprep,
    const float* __restrict__ Beta,
    float* __restrict__ out)
{
    __shared__ alignas(16) unsigned short xsT[NPP][ICP];       // 26208 B
    __shared__ alignas(16) unsigned short Wc[7][9][16][64];    // 129024 B (7 wave strips)
    __shared__ alignas(16) unsigned short BgenT[16][40];       // 1280 B
    __shared__ float xh[2][128];                               // 1024 B
    __shared__ float xhp[4][2][128];                           // 4096 B
    // total 161632 B <= 163840

    const int b = blockIdx.x, t = threadIdx.x;
    const int lane = t & 63, wave = t >> 6;
    const int lrow = lane & 15, jg = lane >> 4;
    const float* xb = x_in + (size_t)b * (CH * NP);

    for (int i = t; i < NPP * ICP / 2; i += 512) ((unsigned int*)xsT)[i] = 0u;
    if (t < 320) ((unsigned int*)BgenT)[t] = 0u;
    __syncthreads();

    // ---- stage x (bf16 transpose) + exact fp32 pool partials, coalesced ----
    {
        int p = (wave & 1) * 64 + lane;     // 0..127
        int ich = wave >> 1;                // 0..3, 16 ics each
        if (p < NP) {
            int pp = (p / HW + 1) * PPW + (p % HW + 1);
            float s = 0.f, m = -INFINITY;
            const float* xc = xb + (ich * 16) * NP + p;
            #pragma unroll 8
            for (int q = 0; q < 16; ++q) {
                float v = xc[q * NP];
                s += v; m = fmaxf(m, v);
                __hip_bfloat16 h = __float2bfloat16(v);
                xsT[pp][ich * 16 + q] = *(unsigned short*)&h;
            }
            xhp[ich][0][p] = s;
            xhp[ich][1][p] = m;
        }
    }
    __syncthreads();
    if (t < NP) {
        xh[0][t] = (xhp[0][0][t] + xhp[1][0][t] + xhp[2][0][t] + xhp[3][0][t]) * (1.f / 64.f);
        xh[1][t] = fmaxf(fmaxf(xhp[0][1][t], xhp[1][1][t]),
                         fmaxf(xhp[2][1][t], xhp[3][1][t]));
    }
    __syncthreads();
    if (t < 162) {   // gen-GEMM B: BgenT[tap][k], k = ci*9+u*3+v (gw flat order)
        int tap = t / 18, k = t - tap * 18;
        int ci = k / 9, o9 = k - ci * 9, u = o9 / 3, v = o9 - u * 3;
        int kh = tap / 3, kw = tap - kh * 3;
        float val = xh[ci][(4 * kh + u) * HW + (4 * kw + v)];
        __hip_bfloat16 h = __float2bfloat16(val);
        BgenT[tap][k] = *(unsigned short*)&h;
    }
    __syncthreads();
    // ================= no __syncthreads below this line =================

    if (wave == 7) return;   // 7 working waves own 16 ocs each (112 padded)

    const bf16x8 Bgen = *(const bf16x8*)&BgenT[lrow][jg * 8];
    char* strip = (char*)&Wc[wave][0][0][0];

    // ---- gen: 64 MFMAs, pack into private strip (dual-XOR 16B-granule swizzle) ----
    #pragma unroll 4
    for (int it = 0; it < 64; ++it) {
        int tG = wave * 64 + it;            // global gen tile < 448
        bf16x8 A = *(const bf16x8*)(Aprep + ((size_t)tG * 64 + lane) * 8);
        f32x4 acc{};
        acc = __builtin_amdgcn_mfma_f32_16x16x32_bf16(A, Bgen, acc, 0, 0, 0);
        float4 bet = *(const float4*)(Beta + tG * 16 + jg * 4);
        if (lrow < 9) {                     // C col = tap = lrow; rows = 4 consecutive ic
            float v0 = fmaxf(acc[0] + bet.x, 0.f);
            float v1 = fmaxf(acc[1] + bet.y, 0.f);
            float v2 = fmaxf(acc[2] + bet.z, 0.f);
            float v3 = fmaxf(acc[3] + bet.w, 0.f);
            __hip_bfloat16 h0 = __float2bfloat16(v0), h1 = __float2bfloat16(v1);
            __hip_bfloat16 h2 = __float2bfloat16(v2), h3 = __float2bfloat16(v3);
            unsigned int lo = (unsigned int)*(unsigned short*)&h0 |
                              ((unsigned int)*(unsigned short*)&h1 << 16);
            unsigned int hi = (unsigned int)*(unsigned short*)&h2 |
                              ((unsigned int)*(unsigned short*)&h3 << 16);
            int oc_l = it >> 2;             // 0..15
            int icb  = it & 3;              // ic block of 16
            int g = (icb * 2 + (jg >> 1)) ^ (lrow & 7) ^ (oc_l & 7);
            uint2 pk; pk.x = lo; pk.y = hi;
            *(uint2*)(strip + lrow * 2048 + oc_l * 128 + g * 16 + (jg & 1) * 8) = pk;
        }
    }

    // ---- readback: 18 A-frags into registers (intra-wave, lgkmcnt only) ----
    bf16x8 Af[18];
    #pragma unroll
    for (int ks = 0; ks < 18; ++ks) {
        int tap = ks >> 1, h = ks & 1;
        int g = (h * 4 + jg) ^ (tap & 7) ^ (lrow & 7);
        Af[ks] = *(const bf16x8*)(strip + tap * 2048 + lrow * 128 + g * 16);
    }

    // ---- main GEMM: 1 M-tile (16 ocs) x 8 N-tiles, N-tiles in pairs ----
    float* ob = out + (size_t)b * 100 * NP;
    #pragma unroll
    for (int ntp = 0; ntp < 4; ++ntp) {
        int p0 = (2 * ntp) * 16 + lrow;
        int p1 = p0 + 16;
        int pc0 = p0 > 120 ? 120 : p0;
        int pc1 = p1 > 120 ? 120 : p1;
        int base0 = (pc0 / HW) * PPW + (pc0 % HW);
        int base1 = (pc1 / HW) * PPW + (pc1 % HW);
        f32x4 a0{}, a1{};
        #pragma unroll
        for (int tap = 0; tap < 9; ++tap) {
            int off = (tap / 3) * PPW + (tap % 3);
            #pragma unroll
            for (int h = 0; h < 2; ++h) {
                bf16x8 B0 = *(const bf16x8*)&xsT[base0 + off][h * 32 + jg * 8];
                bf16x8 B1 = *(const bf16x8*)&xsT[base1 + off][h * 32 + jg * 8];
                a0 = __builtin_amdgcn_mfma_f32_16x16x32_bf16(Af[tap * 2 + h], B0, a0, 0, 0, 0);
                a1 = __builtin_amdgcn_mfma_f32_16x16x32_bf16(Af[tap * 2 + h], B1, a1, 0, 0, 0);
            }
        }
        // C layout: col = lane&15 -> pos, row = jg*4+ri -> oc_local
        #pragma unroll
        for (int ri = 0; ri < 4; ++ri) {
            int oc = wave * 16 + jg * 4 + ri;
            if (oc < 100) {
                if (p0 < NP) ob[oc * NP + p0] = a0[ri];
                if (p1 < NP) ob[oc * NP + p1] = a1[ri];
            }
        }
    }
}

extern "C" void kernel_launch(void* const* d_in, const int* in_sizes, int n_in,
                              void* d_out, int out_size, void* d_ws, size_t ws_size,
                              hipStream_t stream) {
    const float* x  = (const float*)d_in[0];
    const float* gw = (const float*)d_in[1];
    const float* gb = (const float*)d_in[2];
    const float* bg = (const float*)d_in[3];
    const float* bb = (const float*)d_in[4];
    const float* bm = (const float*)d_in[5];
    const float* bv = (const float*)d_in[6];
    float* out = (float*)d_out;

    // ws: Aprep 458752 B | Beta 28672 B   (~476 KiB total)
    unsigned short* Aprep = (unsigned short*)d_ws;
    float* Beta = (float*)((char*)d_ws + 458752);

    const int nb = in_sizes[0] / (CH * NP);  // 1024

    prep_kernel<<<NO / 256, 256, 0, stream>>>(gw, gb, bg, bb, bm, bv, Aprep, Beta);
    hsi_fused<<<nb, 512, 0, stream>>>(x, Aprep, Beta, out);
}

// Round 7
// 111.538 us; speedup vs baseline: 1.5848x; 1.1265x over previous
//
#include <hip/hip_runtime.h>
#include <hip/hip_bf16.h>

using bf16x8 = __attribute__((ext_vector_type(8))) short;
using f32x4  = __attribute__((ext_vector_type(4))) float;

constexpr int CH  = 64;
constexpr int HW  = 11;
constexpr int NP  = 121;
constexpr int PPW = 14;          // padded pos-grid row width
constexpr int ICP = 72;          // ic stride in image (bf16)
constexpr int IMG_CH = 1792;     // int4 chunks per sample image (28672 B, incl pad)
constexpr int IMG_LIVE = 1638;   // 182*72*2/16 real chunks
constexpr int IMG_S = IMG_CH * 8;  // ushort stride per sample (14336)
constexpr int NO  = 7168;        // padded o rows (112 oc * 64 ic)
constexpr float EPS = 1e-5f;

__device__ __forceinline__ f32x4 MFMA(bf16x8 a, bf16x8 b, f32x4 c) {
    return __builtin_amdgcn_mfma_f32_16x16x32_bf16(a, b, c, 0, 0, 0);
}

// ---- prep: bake BN-scaled gw into gen-MFMA A-fragment order + beta ----
__global__ __launch_bounds__(256) void prep_kernel(
    const float* __restrict__ gw, const float* __restrict__ gb,
    const float* __restrict__ bng, const float* __restrict__ bnb,
    const float* __restrict__ bnm, const float* __restrict__ bnv,
    unsigned short* __restrict__ Aprep, float* __restrict__ Beta)
{
    int o = blockIdx.x * 256 + threadIdx.x;
    if (o >= NO) return;
    float inv = 0.f, beta = 0.f;
    if (o < 6400) {
        inv  = bng[o] * rsqrtf(bnv[o] + EPS);
        beta = (gb[o] - bnm[o]) * inv + bnb[o];
    }
    Beta[o] = beta;
    int tile = o >> 4, lrow = o & 15;
    #pragma unroll
    for (int jg = 0; jg < 4; ++jg) {
        bf16x8 f;
        #pragma unroll
        for (int r = 0; r < 8; ++r) {
            int k = jg * 8 + r;
            float v = (o < 6400 && k < 18) ? gw[(size_t)o * 18 + k] * inv : 0.f;
            __hip_bfloat16 h = __float2bfloat16(v);
            f[r] = *(short*)&h;
        }
        ((bf16x8*)Aprep)[tile * 64 + jg * 16 + lrow] = f;
    }
}

// ---- P: pool + padded bf16 transpose image + gen-B matrix, per sample ----
__global__ __launch_bounds__(128) void pool_kernel(
    const float* __restrict__ x_in,
    unsigned short* __restrict__ img,   // [1024][IMG_S]
    unsigned short* __restrict__ Bg)    // [1024][512]
{
    __shared__ float xh[2][128];
    const int phys = blockIdx.x;
    const int b = (phys & 7) * 128 + (phys >> 3);   // XCD-chunked (b/128 = XCD)
    const int t = threadIdx.x;
    const int lane = t & 63, wave = t >> 6;
    const float* xb = x_in + (size_t)b * (CH * NP);
    unsigned short* ib = img + (size_t)b * IMG_S;

    // zero PAD chunks only (disjoint from live fill -> no ordering hazard)
    for (int i = t; i < IMG_CH; i += 128) {
        int row = i / 9, cb = i - row * 9;
        int rq = row / PPW, rm = row - rq * PPW;
        bool live = (i < IMG_LIVE) && (cb < 8) &&
                    (rq >= 1 && rq <= 11) && (rm >= 1 && rm <= 11);
        if (!live) ((int4*)ib)[i] = int4{0, 0, 0, 0};
    }

    // exact fp32 pooling: thread = position, coalesced loads
    if (t < NP) {
        float s = 0.f, m = -INFINITY;
        for (int ic = 0; ic < CH; ++ic) {
            float v = xb[ic * NP + t];
            s += v; m = fmaxf(m, v);
        }
        xh[0][t] = s * (1.f / 64.f);
        xh[1][t] = m;
    }
    __syncthreads();

    // gen-B matrix [tap(16)][k(32)], zero-padded, single write per cell
    for (int i = t; i < 512; i += 128) {
        int tap = i >> 5, k = i & 31;
        float val = 0.f;
        if (tap < 9 && k < 18) {
            int ci = k / 9, o9 = k - ci * 9, u = o9 / 3, v = o9 - u * 3;
            int kh = tap / 3, kw = tap - kh * 3;
            val = xh[ci][(4 * kh + u) * HW + (4 * kw + v)];
        }
        __hip_bfloat16 h = __float2bfloat16(val);
        Bg[b * 512 + i] = *(unsigned short*)&h;
    }

    // transpose live cells: lane = ic, 128B coalesced stores per row
    for (int pos = wave; pos < NP; pos += 2) {
        float v = xb[lane * NP + pos];
        __hip_bfloat16 h = __float2bfloat16(v);
        int pp = (pos / HW + 1) * PPW + (pos % HW + 1);
        ib[pp * ICP + lane] = *(unsigned short*)&h;
    }
}

// ---- main: block = (sample, 16-oc chunk); 1 barrier; 3 blocks/CU ----
__global__ __launch_bounds__(256, 3) void hsi_main(
    const unsigned short* __restrict__ img,
    const unsigned short* __restrict__ Bg,
    const unsigned short* __restrict__ Aprep,
    const float* __restrict__ Beta,
    float* __restrict__ out)
{
    __shared__ alignas(16) unsigned short xsT[IMG_S];        // 28672 B
    __shared__ alignas(16) unsigned short strip[9 * 16 * 64]; // 18432 B
    // total 47104 B -> 3 blocks/CU

    const int phys = blockIdx.x;
    const int L = (phys & 7) * 896 + (phys >> 3);   // XCD-chunked bijection
    const int b = L / 7, c = L - b * 7;             // sample, oc-chunk
    const int t = threadIdx.x;
    const int lane = t & 63, wave = t >> 6;
    const int lrow = lane & 15, jg = lane >> 4;

    // 1) issue image loads early (hide under gen)
    const int4* ibv = (const int4*)(img + (size_t)b * IMG_S);
    int4 st[7];
    #pragma unroll
    for (int k = 0; k < 7; ++k) st[k] = ibv[t + k * 256];

    // 2) gen-B fragment (16B coalesced per lane)
    const bf16x8 Bgen = *(const bf16x8*)(Bg + b * 512 + lrow * 32 + jg * 8);

    // 3) gen: 16 MFMAs/wave, pack -> shared strip (dual-XOR swizzle, R6-verified)
    char* sp = (char*)strip;
    #pragma unroll 4
    for (int it = 0; it < 16; ++it) {
        int tl = wave * 16 + it;          // chunk-local gen tile
        int tG = c * 64 + tl;             // global tile < 448
        bf16x8 A = *(const bf16x8*)(Aprep + ((size_t)tG * 64 + lane) * 8);
        f32x4 acc{};
        acc = MFMA(A, Bgen, acc);
        float4 bet = *(const float4*)(Beta + tG * 16 + jg * 4);
        if (lrow < 9) {                   // C col = tap = lrow; rows = 4 ics
            float v0 = fmaxf(acc[0] + bet.x, 0.f);
            float v1 = fmaxf(acc[1] + bet.y, 0.f);
            float v2 = fmaxf(acc[2] + bet.z, 0.f);
            float v3 = fmaxf(acc[3] + bet.w, 0.f);
            __hip_bfloat16 h0 = __float2bfloat16(v0), h1 = __float2bfloat16(v1);
            __hip_bfloat16 h2 = __float2bfloat16(v2), h3 = __float2bfloat16(v3);
            unsigned int lo = (unsigned int)*(unsigned short*)&h0 |
                              ((unsigned int)*(unsigned short*)&h1 << 16);
            unsigned int hi = (unsigned int)*(unsigned short*)&h2 |
                              ((unsigned int)*(unsigned short*)&h3 << 16);
            int oc_l = tl >> 2;           // 0..15
            int icb  = tl & 3;
            int g = (icb * 2 + (jg >> 1)) ^ (lrow & 7) ^ (oc_l & 7);
            uint2 pk; pk.x = lo; pk.y = hi;
            *(uint2*)(sp + lrow * 2048 + oc_l * 128 + g * 16 + (jg & 1) * 8) = pk;
        }
    }

    // 4) write staged image into LDS
    int4* xv = (int4*)xsT;
    #pragma unroll
    for (int k = 0; k < 7; ++k) xv[t + k * 256] = st[k];

    __syncthreads();   // the only barrier

    // 5) readback A-fragments (16 ocs x K=576, tap-major)
    bf16x8 Af[18];
    #pragma unroll
    for (int ks = 0; ks < 18; ++ks) {
        int tap = ks >> 1, h = ks & 1;
        int g = (h * 4 + jg) ^ (tap & 7) ^ (lrow & 7);
        Af[ks] = *(const bf16x8*)(sp + tap * 2048 + lrow * 128 + g * 16);
    }

    // 6) main GEMM: wave owns 2 N-tiles; store
    float* ob = out + (size_t)b * 100 * NP;
    #pragma unroll
    for (int ntp = 0; ntp < 2; ++ntp) {
        int p = (wave * 2 + ntp) * 16 + lrow;
        int pc = p > 120 ? 120 : p;
        int base = (pc / HW) * PPW + (pc % HW);
        f32x4 acc{};
        #pragma unroll
        for (int tap = 0; tap < 9; ++tap) {
            int off = base + (tap / 3) * PPW + (tap % 3);
            #pragma unroll
            for (int h = 0; h < 2; ++h) {
                bf16x8 B = *(const bf16x8*)&xsT[off * ICP + h * 32 + jg * 8];
                acc = MFMA(Af[tap * 2 + h], B, acc);
            }
        }
        if (p < NP) {
            #pragma unroll
            for (int ri = 0; ri < 4; ++ri) {
                int oc = c * 16 + jg * 4 + ri;
                if (oc < 100) ob[oc * NP + p] = acc[ri];
            }
        }
    }
}

extern "C" void kernel_launch(void* const* d_in, const int* in_sizes, int n_in,
                              void* d_out, int out_size, void* d_ws, size_t ws_size,
                              hipStream_t stream) {
    const float* x  = (const float*)d_in[0];
    const float* gw = (const float*)d_in[1];
    const float* gb = (const float*)d_in[2];
    const float* bg = (const float*)d_in[3];
    const float* bb = (const float*)d_in[4];
    const float* bm = (const float*)d_in[5];
    const float* bv = (const float*)d_in[6];
    float* out = (float*)d_out;

    // ws: Aprep 458752 | Beta 28672 | Bg 1048576 | img 1024*28672  (~30.9 MiB)
    unsigned short* Aprep = (unsigned short*)d_ws;
    float* Beta = (float*)((char*)d_ws + 458752);
    unsigned short* Bgm = (unsigned short*)((char*)d_ws + 487424);
    unsigned short* img = (unsigned short*)((char*)d_ws + 1536000);

    prep_kernel<<<NO / 256, 256, 0, stream>>>(gw, gb, bg, bb, bm, bv, Aprep, Beta);
    pool_kernel<<<1024, 128, 0, stream>>>(x, img, Bgm);
    hsi_main<<<1024 * 7, 256, 0, stream>>>(img, Bgm, Aprep, Beta, out);
}